// Round 7
// baseline (714.391 us; speedup 1.0000x reference)
//
#include <hip/hip_runtime.h>
#include <hip/hip_bf16.h>
#include <math.h>

// Problem constants (from reference)
#define BB 2
#define TT 256
#define BT 512      // B*T
#define EE 512
#define GG 8
#define GD 64
#define LL 8
#define NN 64
#define VV 50257
#define D2 32
#define EPS 1.1920928955078125e-07f
#define S72 72      // LDS row stride in bf16 (144 B -> 2-way bank alias = free)

typedef __attribute__((ext_vector_type(4))) float floatx4;
typedef __attribute__((ext_vector_type(8))) short short8;

// unaligned-capable 16B store (out rows have odd dword stride VV=50257)
struct __attribute__((packed, aligned(4))) f4u { float x, y, z, w; };

// ---------------- workspace layout (float offsets) ----------------
#define OFF_DEPTHS   0
#define OFF_APS      64
#define OFF_MPS      (OFF_APS + NN*GD)            // 4160
#define OFF_COS      (OFF_MPS + NN*GD)            // 8256
#define OFF_SIN      (OFF_COS + TT*D2)            // 16448
#define OFF_X        (OFF_SIN + TT*D2)            // 24640
#define OFF_PCONT    (OFF_X + BT*EE)              // 286784
#define OFF_SMLP     (OFF_PCONT + BT)             // 287296
#define OFF_YBF      (OFF_SMLP + BT*NN)           // 320064 (bf16 BT*EE)
// step-loop region (dead after loop; wbf overlays it)
#define OFF_STEP     (OFF_YBF + (BT*EE)/2)        // 451136
#define OFF_XI       OFF_STEP                     // fp32 BT*NN*GD
#define OFF_ATT      (OFF_XI + BT*NN*GD)          // fp32
#define OFF_XBF      (OFF_ATT + BT*NN*GD)         // bf16 BT*EE
#define OFF_QB       (OFF_XBF + (BT*EE)/2)        // bf16 BT*NN*GD
#define OFF_KB       (OFF_QB + (BT*NN*GD)/2)
#define OFF_VTB      (OFF_KB + (BT*NN*GD)/2)      // bf16, transposed [b][n][g][t]
#define OFF_ABF      (OFF_VTB + (BT*NN*GD)/2)     // bf16 NN*GD*EE
#define OFF_QWBF     (OFF_ABF + (NN*GD*EE)/2)     // bf16 NN*192*GD
#define OFF_FWBF     (OFF_QWBF + (NN*192*GD)/2)   // bf16 NN*256*GD
// after step loop: wbf overlays OFF_STEP..
#define OFF_WBF      OFF_STEP                     // bf16 VV*EE

__device__ __forceinline__ float step_weight(const float* depths, const int* ns, int t, int n) {
    float td = (float)t * (8.0f / (float)ns[0]);
    float wa = expf(-fabsf(depths[n] - td));
    return (wa > 0.15f) ? wa : 0.0f;
}

__device__ __forceinline__ float fast_tanh15(float v) {
    // 15*tanh(v/15) = 15*(1 - 2/(e^{2v/15}+1)); fast exp+div, err << bf16 noise
    float u = v * (1.f/15.f);
    float e = __expf(2.f * u);
    return 15.f * (1.f - __fdividef(2.f, e + 1.f));
}

__global__ void k_prep(const float* __restrict__ dep, float* __restrict__ depths) {
    __shared__ float cur[NN], nxt[NN];
    int i = threadIdx.x;
    if (i < NN) cur[i] = 0.f;
    __syncthreads();
    for (int it = 0; it < LL; ++it) {
        if (i < NN) {
            float acc = 0.f;
            for (int m = 0; m < NN; ++m) acc += fmaxf(dep[i*NN + m], 0.f) * (cur[m] + 1.f);
            nxt[i] = acc;
        }
        __syncthreads();
        if (i < NN) cur[i] = nxt[i];
        __syncthreads();
    }
    if (i < NN) depths[i] = cur[i];
}

__global__ void k_sums(const float* __restrict__ attn_proj, const float* __restrict__ mlp_proj,
                       float* __restrict__ aps, float* __restrict__ mps) {
    int i = blockIdx.x * blockDim.x + threadIdx.x;
    if (i >= NN*GD) return;
    float a = 0.f;
    const float* ap = attn_proj + (size_t)i * GD;
    for (int k = 0; k < GD; ++k) a += ap[k];
    aps[i] = a;
    float m = 0.f;
    const float* mp = mlp_proj + (size_t)i * 4 * GD;
    for (int k = 0; k < 4*GD; ++k) m += mp[k];
    mps[i] = m;
}

__global__ void k_rope_table(float* __restrict__ ctab, float* __restrict__ stab) {
    int i = blockIdx.x * blockDim.x + threadIdx.x;
    if (i >= TT*D2) return;
    int pos = i / D2, f = i % D2;
    double inv = pow(10000.0, -((double)(2*f)) / (double)GD);
    double ang = (double)pos * inv;
    ctab[i] = (float)cos(ang);
    stab[i] = (float)sin(ang);
}

// generic f32 -> bf16 (4 elems/thread), packed 8B store
__global__ void k_cvt(const float* __restrict__ src, __hip_bfloat16* __restrict__ dst, int n4) {
    int i = blockIdx.x * blockDim.x + threadIdx.x;
    if (i >= n4) return;
    float4 f = ((const float4*)src)[i];
    __hip_bfloat16 h0 = __float2bfloat16(f.x);
    __hip_bfloat16 h1 = __float2bfloat16(f.y);
    __hip_bfloat16 h2 = __float2bfloat16(f.z);
    __hip_bfloat16 h3 = __float2bfloat16(f.w);
    ushort4 o;
    o.x = *(const unsigned short*)&h0;
    o.y = *(const unsigned short*)&h1;
    o.z = *(const unsigned short*)&h2;
    o.w = *(const unsigned short*)&h3;
    *(ushort4*)(dst + (size_t)i*4) = o;
}

__global__ void k_embed(const int* __restrict__ idx, const float* __restrict__ wte,
                        float* __restrict__ x, __hip_bfloat16* __restrict__ xbf,
                        float* __restrict__ pcont) {
    int bt = blockIdx.x;
    int tid = threadIdx.x;
    const float* src = wte + (size_t)idx[bt] * EE;
    float v0 = src[tid], v1 = src[tid + 256];
    __shared__ float red[4];
    float ss = v0*v0 + v1*v1;
    for (int o = 32; o > 0; o >>= 1) ss += __shfl_xor(ss, o);
    if ((tid & 63) == 0) red[tid >> 6] = ss;
    __syncthreads();
    float sc = rsqrtf((red[0]+red[1]+red[2]+red[3]) / (float)EE + EPS);
    float a = v0 * sc, b = v1 * sc;
    x[bt*EE + tid]       = a;
    x[bt*EE + tid + 256] = b;
    xbf[bt*EE + tid]       = __float2bfloat16(a);
    xbf[bt*EE + tid + 256] = __float2bfloat16(b);
    if (tid == 0) pcont[bt] = 1.f;
}

// ---- Fused xi + qkv + rope + rms, bf16 MFMA.  grid (BT/64, NN), 256 thr. ----
// Phase-1: linear [2][64][64] LDS tiles staged by global_load_lds width-16,
// chunk-XOR swizzle on source+read, 2-phase prefetch dbuf (WIN: latency-bound
// at ~192 blocks, prefetch is the only latency hider). 42.2 KB LDS.
__global__ __launch_bounds__(256) void k_xi_qkv(const __hip_bfloat16* __restrict__ xbf,
        const __hip_bfloat16* __restrict__ abf, const __hip_bfloat16* __restrict__ qwbf,
        const float* __restrict__ x, float* __restrict__ xi,
        __hip_bfloat16* __restrict__ qb, __hip_bfloat16* __restrict__ kb,
        __hip_bfloat16* __restrict__ vtb,
        const float* __restrict__ ctab, const float* __restrict__ stab,
        const float* __restrict__ depths, const int* __restrict__ ns, int t) {
    int n = blockIdx.y;
    if (step_weight(depths, ns, t, n) == 0.f) return;
    int bt0 = blockIdx.x * 64;
    // region0 [0,16640): obuf(fp32 64*65) ∪ sA[2][4096]
    // region1 [16640,33024): sB[2][4096] ∪ Bs72[64*S72]
    // region2 [33024,42240): xis[64*S72]
    __shared__ __align__(16) char smem[16640 + 16384 + 9216];
    __hip_bfloat16* sA   = (__hip_bfloat16*)smem;
    float*          obuf = (float*)smem;
    __hip_bfloat16* sB   = (__hip_bfloat16*)(smem + 16640);
    __hip_bfloat16* Bs72 = (__hip_bfloat16*)(smem + 16640);
    __hip_bfloat16* xis  = (__hip_bfloat16*)(smem + 33024);
    int tid = threadIdx.x;
    int wave = tid >> 6, lane = tid & 63;
    int wr = wave >> 1, wc = wave & 1;
    int quad = lane >> 4, l16 = lane & 15;

    // ---- phase 1: xi = xbf @ abf[n]^T  (64 tok x 64 g, K=512) ----
    size_t goffA[2], goffB[2];
    int sOff[2];
    #pragma unroll
    for (int j = 0; j < 2; ++j) {
        int s = (j*4 + wave)*64 + lane;   // chunk id 0..511
        int r = s >> 3;                   // tile row 0..63
        int cs = (s & 7) ^ (r & 7);       // swizzled source chunk
        goffA[j] = (size_t)(bt0 + r)*EE + cs*8;
        goffB[j] = ((size_t)n*GD + r)*EE + cs*8;
        sOff[j] = (j*4 + wave)*512;       // bf16 elems; wave-uniform
    }

    floatx4 acc[2][2];
    #pragma unroll
    for (int mt = 0; mt < 2; ++mt)
        #pragma unroll
        for (int nt = 0; nt < 2; ++nt) acc[mt][nt] = (floatx4){0.f,0.f,0.f,0.f};

    // prologue: stage kt=0 into buffer 0
    #pragma unroll
    for (int j = 0; j < 2; ++j) {
        __builtin_amdgcn_global_load_lds(
            (const __attribute__((address_space(1))) void*)(xbf + goffA[j]),
            (__attribute__((address_space(3))) void*)(&sA[sOff[j]]), 16, 0, 0);
        __builtin_amdgcn_global_load_lds(
            (const __attribute__((address_space(1))) void*)(abf + goffB[j]),
            (__attribute__((address_space(3))) void*)(&sB[sOff[j]]), 16, 0, 0);
    }
    __syncthreads();

    int cur = 0;
    #pragma unroll
    for (int kt = 0; kt < 8; ++kt) {
        if (kt < 7) {
            int k0 = (kt + 1) * 64;
            #pragma unroll
            for (int j = 0; j < 2; ++j) {
                __builtin_amdgcn_global_load_lds(
                    (const __attribute__((address_space(1))) void*)(xbf + goffA[j] + k0),
                    (__attribute__((address_space(3))) void*)(&sA[(cur^1)*4096 + sOff[j]]), 16, 0, 0);
                __builtin_amdgcn_global_load_lds(
                    (const __attribute__((address_space(1))) void*)(abf + goffB[j] + k0),
                    (__attribute__((address_space(3))) void*)(&sB[(cur^1)*4096 + sOff[j]]), 16, 0, 0);
            }
        }
        #pragma unroll
        for (int ks = 0; ks < 2; ++ks) {
            short8 af[2], bf[2];
            #pragma unroll
            for (int mt = 0; mt < 2; ++mt) {
                int row = wr*32 + mt*16 + l16;
                int ck = ((ks << 2) | quad) ^ (row & 7);
                af[mt] = *(const short8*)(&sA[cur*4096 + row*64 + ck*8]);
            }
            #pragma unroll
            for (int nt = 0; nt < 2; ++nt) {
                int row = wc*32 + nt*16 + l16;
                int ck = ((ks << 2) | quad) ^ (row & 7);
                bf[nt] = *(const short8*)(&sB[cur*4096 + row*64 + ck*8]);
            }
            #pragma unroll
            for (int mt = 0; mt < 2; ++mt)
                #pragma unroll
                for (int nt = 0; nt < 2; ++nt)
                    acc[mt][nt] = __builtin_amdgcn_mfma_f32_16x16x32_bf16(af[mt], bf[nt], acc[mt][nt], 0, 0, 0);
        }
        __syncthreads();
        cur ^= 1;
    }

    int gofs = (n & (GG-1)) * GD;
    #pragma unroll
    for (int mt = 0; mt < 2; ++mt) {
        #pragma unroll
        for (int nt = 0; nt < 2; ++nt) {
            int col = wc*32 + nt*16 + l16;
            #pragma unroll
            for (int r = 0; r < 4; ++r) {
                int token = wr*32 + mt*16 + quad*4 + r;
                int bt = bt0 + token;
                float val = acc[mt][nt][r] + x[(size_t)bt*EE + gofs + col];
                xi[((size_t)bt*NN + n)*GD + col] = val;
                xis[token*S72 + col] = __float2bfloat16(val);
            }
        }
    }
    __syncthreads();

    // ---- phase 2: qkv = xis @ qkv_w[n]^T (per c: 64 tok x 64 out, K=64) ----
    const __hip_bfloat16* wbase = qwbf + (size_t)n * 192 * GD;
    int b = bt0 >> 8;           // batch index
    int t0 = bt0 & (TT - 1);    // position of first token in tile
    for (int c = 0; c < 3; ++c) {
        for (int i = tid; i < 512; i += 256) {
            int r = i >> 3, c8 = (i & 7) * 8;
            *(uint4*)(&Bs72[r*S72 + c8]) = *(const uint4*)(&wbase[(size_t)(c*64 + r)*GD + c8]);
        }
        __syncthreads();
        floatx4 oacc[2][2];
        #pragma unroll
        for (int mt = 0; mt < 2; ++mt)
            #pragma unroll
            for (int nt = 0; nt < 2; ++nt) oacc[mt][nt] = (floatx4){0.f,0.f,0.f,0.f};
        #pragma unroll
        for (int ks = 0; ks < 2; ++ks) {
            short8 af[2], bf[2];
            #pragma unroll
            for (int mt = 0; mt < 2; ++mt)
                af[mt] = *(const short8*)(&xis[(wr*32 + mt*16 + l16)*S72 + ks*32 + quad*8]);
            #pragma unroll
            for (int nt = 0; nt < 2; ++nt)
                bf[nt] = *(const short8*)(&Bs72[(wc*32 + nt*16 + l16)*S72 + ks*32 + quad*8]);
            #pragma unroll
            for (int mt = 0; mt < 2; ++mt)
                #pragma unroll
                for (int nt = 0; nt < 2; ++nt)
                    oacc[mt][nt] = __builtin_amdgcn_mfma_f32_16x16x32_bf16(af[mt], bf[nt], oacc[mt][nt], 0, 0, 0);
        }
        #pragma unroll
        for (int mt = 0; mt < 2; ++mt)
            #pragma unroll
            for (int nt = 0; nt < 2; ++nt)
                #pragma unroll
                for (int r = 0; r < 4; ++r)
                    obuf[(wr*32 + mt*16 + quad*4 + r)*65 + wc*32 + nt*16 + l16] = oacc[mt][nt][r];
        __syncthreads();
        if (c < 2) {
            // rope + rms per token-row, write bf16
            __hip_bfloat16* dst = (c == 0) ? qb : kb;
            for (int tr = 0; tr < 16; ++tr) {
                int row = wave*16 + tr, bt = bt0 + row;
                float val = obuf[row*65 + lane];
                int pos = bt & (TT - 1);
                float pair = __shfl_xor(val, 32);
                int fi = lane & 31;
                float cc = ctab[pos*D2 + fi], sn = stab[pos*D2 + fi];
                float nv = (lane < 32) ? (val*cc + pair*sn) : (val*cc - pair*sn);
                float ss = nv*nv;
                for (int o = 32; o > 0; o >>= 1) ss += __shfl_xor(ss, o);
                float outv = nv * rsqrtf(ss / (float)GD + EPS);
                dst[((size_t)bt*NN + n)*GD + lane] = __float2bfloat16(outv);
            }
        } else {
            // v: read obuf transposed (conflict-free), write coalesced to vtb[b][n][g][t]
            for (int tr = 0; tr < 16; ++tr) {
                int g = wave*16 + tr;
                float vv = obuf[lane*65 + g];
                vtb[(((size_t)(b*NN + n))*GD + g)*TT + t0 + lane] = __float2bfloat16(vv);
            }
        }
        __syncthreads();
    }
}

// ---- Flash attention, bf16 MFMA.  grid (4, B, NN), 256 thr (4 waves, 16 rows each). ----
__global__ __launch_bounds__(256) void k_attn(const __hip_bfloat16* __restrict__ qb,
        const __hip_bfloat16* __restrict__ kb, const __hip_bfloat16* __restrict__ vtb,
        float* __restrict__ att,
        const float* __restrict__ depths, const int* __restrict__ ns, int t) {
    int it = blockIdx.x, b = blockIdx.y, n = blockIdx.z;
    if (step_weight(depths, ns, t, n) == 0.f) return;
    __shared__ __align__(16) __hip_bfloat16 qs[64*S72];
    __shared__ __align__(16) __hip_bfloat16 ksm[64*S72];
    __shared__ __align__(16) __hip_bfloat16 vs[64*S72];
    __shared__ __align__(16) __hip_bfloat16 ps[64*S72];
    int tid = threadIdx.x;
    int wave = tid >> 6, lane = tid & 63;
    int quad = lane >> 4, l16 = lane & 15;
    for (int i = tid; i < 512; i += 256) {
        int r = i >> 3, c8 = (i & 7) * 8;
        *(uint4*)(&qs[r*S72 + c8]) = *(const uint4*)(&qb[(((size_t)(b*TT + it*64 + r))*NN + n)*GD + c8]);
    }
    floatx4 oacc[4];
    float m_i[4], l_i[4];
    #pragma unroll
    for (int nt = 0; nt < 4; ++nt) oacc[nt] = (floatx4){0.f,0.f,0.f,0.f};
    #pragma unroll
    for (int r = 0; r < 4; ++r) { m_i[r] = -INFINITY; l_i[r] = 0.f; }
    __syncthreads();
    for (int ct = 0; ct <= it; ++ct) {
        for (int i = tid; i < 512; i += 256) {
            int r = i >> 3, c8 = (i & 7) * 8;
            *(uint4*)(&ksm[r*S72 + c8]) = *(const uint4*)(&kb[(((size_t)(b*TT + ct*64 + r))*NN + n)*GD + c8]);
            *(uint4*)(&vs[r*S72 + c8])  = *(const uint4*)(&vtb[(((size_t)(b*NN + n))*GD + r)*TT + ct*64 + c8]);
        }
        __syncthreads();
        // S = Q K^T : rows = wave*16.., cols = full 64
        floatx4 s[4];
        #pragma unroll
        for (int nt = 0; nt < 4; ++nt) s[nt] = (floatx4){0.f,0.f,0.f,0.f};
        #pragma unroll
        for (int ks = 0; ks < 2; ++ks) {
            short8 af = *(const short8*)(&qs[(wave*16 + l16)*S72 + ks*32 + quad*8]);
            #pragma unroll
            for (int nt = 0; nt < 4; ++nt) {
                short8 bf = *(const short8*)(&ksm[(nt*16 + l16)*S72 + ks*32 + quad*8]);
                s[nt] = __builtin_amdgcn_mfma_f32_16x16x32_bf16(af, bf, s[nt], 0, 0, 0);
            }
        }
        // online softmax per row (row = wave*16 + quad*4 + r)
        #pragma unroll
        for (int r = 0; r < 4; ++r) {
            int rowg = it*64 + wave*16 + quad*4 + r;
            float mx = -INFINITY;
            #pragma unroll
            for (int nt = 0; nt < 4; ++nt) {
                int colg = ct*64 + nt*16 + l16;
                float sv = (colg <= rowg) ? s[nt][r] * 0.125f : -INFINITY;
                s[nt][r] = sv;
                mx = fmaxf(mx, sv);
            }
            for (int o = 8; o > 0; o >>= 1) mx = fmaxf(mx, __shfl_xor(mx, o));
            float mnew = fmaxf(m_i[r], mx);
            float alpha = expf(m_i[r] - mnew);
            float rs = 0.f;
            #pragma unroll
            for (int nt = 0; nt < 4; ++nt) {
                float p = expf(s[nt][r] - mnew);
                s[nt][r] = p;
                rs += p;
            }
            for (int o = 8; o > 0; o >>= 1) rs += __shfl_xor(rs, o);
            l_i[r] = l_i[r]*alpha + rs;
            m_i[r] = mnew;
            #pragma unroll
            for (int nt = 0; nt < 4; ++nt) oacc[nt][r] *= alpha;
        }
        // P -> LDS (A-layout rows = q-token)
        #pragma unroll
        for (int nt = 0; nt < 4; ++nt)
            #pragma unroll
            for (int r = 0; r < 4; ++r)
                ps[(wave*16 + quad*4 + r)*S72 + nt*16 + l16] = __float2bfloat16(s[nt][r]);
        __syncthreads();
        // O += P V : B-operand rows = g (vtb transposed), k = ct-token
        #pragma unroll
        for (int ks = 0; ks < 2; ++ks) {
            short8 af = *(const short8*)(&ps[(wave*16 + l16)*S72 + ks*32 + quad*8]);
            #pragma unroll
            for (int nt = 0; nt < 4; ++nt) {
                short8 bf = *(const short8*)(&vs[(nt*16 + l16)*S72 + ks*32 + quad*8]);
                oacc[nt] = __builtin_amdgcn_mfma_f32_16x16x32_bf16(af, bf, oacc[nt], 0, 0, 0);
            }
        }
        __syncthreads();
    }
    #pragma unroll
    for (int r = 0; r < 4; ++r) {
        float inv = 1.f / l_i[r];
        int token = it*64 + wave*16 + quad*4 + r;
        #pragma unroll
        for (int nt = 0; nt < 4; ++nt)
            att[((size_t)(b*TT + token)*NN + n)*GD + nt*16 + l16] = oacc[nt][r] * inv;
    }
}

// ---- fc: smlp = sum_o relu(mlp_fc[n] @ rms(xi+att*aps))^2, bf16 MFMA.  grid (BT/64, NN). ----
__global__ __launch_bounds__(256) void k_fc2(const float* __restrict__ xi, const float* __restrict__ att,
        const float* __restrict__ aps, const __hip_bfloat16* __restrict__ fwbf, float* __restrict__ smlp,
        const float* __restrict__ depths, const int* __restrict__ ns, int t) {
    int n = blockIdx.y;
    if (step_weight(depths, ns, t, n) == 0.f) return;
    int bt0 = blockIdx.x * 64;
    __shared__ __align__(16) __hip_bfloat16 ys[64*S72];
    __shared__ __align__(16) __hip_bfloat16 ws[64*S72];
    __shared__ float sred[64];
    int tid = threadIdx.x;
    int wave = tid >> 6, lane = tid & 63;
    int quad = lane >> 4, l16 = lane & 15;
    for (int tr = 0; tr < 16; ++tr) {
        int row = wave*16 + tr, bt = bt0 + row;
        size_t base = ((size_t)bt*NN + n)*GD + lane;
        float xv = xi[base] + att[base] * aps[n*GD + lane];
        float ss = xv*xv;
        for (int o = 32; o > 0; o >>= 1) ss += __shfl_xor(ss, o);
        ys[row*S72 + lane] = __float2bfloat16(xv * rsqrtf(ss / (float)GD + EPS));
    }
    __syncthreads();
    float rowacc[4] = {0.f, 0.f, 0.f, 0.f};
    for (int c = 0; c < 4; ++c) {
        for (int i = tid; i < 512; i += 256) {
            int r = i >> 3, c8 = (i & 7) * 8;
            *(uint4*)(&ws[r*S72 + c8]) = *(const uint4*)(&fwbf[((size_t)n*256 + c*64 + r)*GD + c8]);
        }
        __syncthreads();
        floatx4 s[4];
        #pragma unroll
        for (int nt = 0; nt < 4; ++nt) s[nt] = (floatx4){0.f,0.f,0.f,0.f};
        #pragma unroll
        for (int ks = 0; ks < 2; ++ks) {
            short8 af = *(const short8*)(&ys[(wave*16 + l16)*S72 + ks*32 + quad*8]);
            #pragma unroll
            for (int nt = 0; nt < 4; ++nt) {
                short8 bf = *(const short8*)(&ws[(nt*16 + l16)*S72 + ks*32 + quad*8]);
                s[nt] = __builtin_amdgcn_mfma_f32_16x16x32_bf16(af, bf, s[nt], 0, 0, 0);
            }
        }
        #pragma unroll
        for (int nt = 0; nt < 4; ++nt)
            #pragma unroll
            for (int r = 0; r < 4; ++r) {
                float rr = fmaxf(s[nt][r], 0.f);
                rowacc[r] += rr*rr;
            }
        __syncthreads();
    }
    #pragma unroll
    for (int r = 0; r < 4; ++r) {
        for (int o = 8; o > 0; o >>= 1) rowacc[r] += __shfl_xor(rowacc[r], o);
        if (l16 == 0) sred[wave*16 + quad*4 + r] = rowacc[r];
    }
    __syncthreads();
    if (tid < 64) smlp[(size_t)(bt0 + tid)*NN + n] = sred[tid];
}

// last!=0: final step — skip xbf store, fuse rms conversion (write ybf) here.
__global__ __launch_bounds__(256) void k_update(float* __restrict__ x, __hip_bfloat16* __restrict__ xbf,
                                                float* __restrict__ pcont,
                                                const float* __restrict__ att, const float* __restrict__ smlp,
                                                const float* __restrict__ aps, const float* __restrict__ mps,
                                                const float* __restrict__ router_w, const float* __restrict__ router_b,
                                                const float* __restrict__ depths, const int* __restrict__ ns, int t,
                                                int last, __hip_bfloat16* __restrict__ ybf) {
    int bt = blockIdx.x, tid = threadIdx.x;
    __shared__ float we[NN];
    __shared__ float red[4];
    __shared__ float red2[4];
    if (tid < NN) we[tid] = step_weight(depths, ns, t, tid);
    __syncthreads();
    float pc = pcont[bt];
    float dot = 0.f, ssq = 0.f;
    float xv0 = 0.f, xv1 = 0.f;
    #pragma unroll
    for (int h = 0; h < 2; ++h) {
        int e = tid + h*256;
        int gq = e >> 6, gd = e & 63;
        float sum = 0.f;
        #pragma unroll
        for (int l = 0; l < LL; ++l) {
            int n = l*GG + gq;
            float w = we[n];
            if (w != 0.f) {
                sum += (att[((size_t)bt*NN + n)*GD + gd] * aps[n*GD + gd]
                        + smlp[bt*NN + n] * mps[n*GD + gd]) * w;
            }
        }
        float xv = x[bt*EE + e] + sum * pc;
        x[bt*EE + e] = xv;
        if (!last) xbf[bt*EE + e] = __float2bfloat16(xv);
        dot += xv * router_w[e];
        ssq += xv * xv;
        if (h == 0) xv0 = xv; else xv1 = xv;
    }
    for (int o = 32; o > 0; o >>= 1) dot += __shfl_xor(dot, o);
    if (last) for (int o = 32; o > 0; o >>= 1) ssq += __shfl_xor(ssq, o);
    if ((tid & 63) == 0) { red[tid >> 6] = dot; red2[tid >> 6] = ssq; }
    __syncthreads();
    if (last) {
        float sc = rsqrtf((red2[0]+red2[1]+red2[2]+red2[3]) / (float)EE + EPS);
        ybf[bt*EE + tid]       = __float2bfloat16(xv0 * sc);
        ybf[bt*EE + tid + 256] = __float2bfloat16(xv1 * sc);
    }
    if (tid == 0) {
        float z = red[0]+red[1]+red[2]+red[3] + router_b[0];
        float ph = 1.f / (1.f + expf(-z));
        pcont[bt] = pc * (1.f - ph);
    }
}

// out = 15*tanh((rms(x) @ W^T)/15), bf16 MFMA.
// K-loop: round-2-verified single-buffer structure (32 KB LDS -> 5 blocks/CU TLP).
// Chunk-XOR swizzle on source+read (rule #21), conflict-free ds_read_b128.
// NEW: LDS-transpose epilogue — acc dumped to padded fp32 LDS per mt, re-read as
// 4-consecutive-cols/lane, stored 16 B/lane (512 B contiguous per row per 32 lanes).
// Was: 64 scalar stores/thread = 64 B write granules at ~1.5 TB/s effective.
__global__ __launch_bounds__(256) void k_lmhead(const __hip_bfloat16* __restrict__ ybf,
                                                const __hip_bfloat16* __restrict__ wbf,
                                                float* __restrict__ out) {
    int id = blockIdx.x;
    int w = (id & 7) * 200 + (id >> 3);   // bijective chunked XCD swizzle (1600 = 8*200)
    int bm = w & 3;
    int bn = w >> 2;
    if (bn >= (VV + 127)/128) return;

    __shared__ __align__(16) char smem[32768];
    __hip_bfloat16* As  = (__hip_bfloat16*)smem;            // [128*64]
    __hip_bfloat16* Bs  = (__hip_bfloat16*)(smem + 16384);  // [128*64]
    float*          ebuf = (float*)smem;                    // epilogue 32x132 fp32 (16.9 KB)

    int tid = threadIdx.x;
    int wave = tid >> 6, lane = tid & 63;
    int wr = wave >> 1, wc = wave & 1;
    int quad = lane >> 4, l16 = lane & 15;

    size_t offA[4], offB[4];
    int ldsOff[4];
    #pragma unroll
    for (int j = 0; j < 4; ++j) {
        int s = (j*4 + wave)*64 + lane;   // chunk id 0..1023
        int r = s >> 3;                   // tile row 0..127
        int cs = (s & 7) ^ (r & 7);       // swizzled source chunk 0..7
        offA[j] = (size_t)(bm*128 + r)*EE + cs*8;
        int vrow = bn*128 + r; if (vrow >= VV) vrow = VV - 1;
        offB[j] = (size_t)vrow*EE + cs*8;
        ldsOff[j] = (j*4 + wave)*512;     // bf16 elems; wave-uniform
    }

    floatx4 acc[4][4];
    #pragma unroll
    for (int mt = 0; mt < 4; ++mt)
        #pragma unroll
        for (int nt = 0; nt < 4; ++nt)
            acc[mt][nt] = (floatx4){0.f, 0.f, 0.f, 0.f};

    for (int k0 = 0; k0 < EE; k0 += 64) {
        #pragma unroll
        for (int j = 0; j < 4; ++j) {
            __builtin_amdgcn_global_load_lds(
                (const __attribute__((address_space(1))) void*)(ybf + offA[j] + k0),
                (__attribute__((address_space(3))) void*)(&As[ldsOff[j]]), 16, 0, 0);
            __builtin_amdgcn_global_load_lds(
                (const __attribute__((address_space(1))) void*)(wbf + offB[j] + k0),
                (__attribute__((address_space(3))) void*)(&Bs[ldsOff[j]]), 16, 0, 0);
        }
        __syncthreads();
        #pragma unroll
        for (int ks = 0; ks < 2; ++ks) {
            short8 af[4], bf[4];
            #pragma unroll
            for (int mt = 0; mt < 4; ++mt) {
                int r = wr*64 + mt*16 + l16;
                int ck = ((ks << 2) | quad) ^ (r & 7);
                af[mt] = *(const short8*)(&As[r*64 + ck*8]);
            }
            #pragma unroll
            for (int nt = 0; nt < 4; ++nt) {
                int r = wc*64 + nt*16 + l16;
                int ck = ((ks << 2) | quad) ^ (r & 7);
                bf[nt] = *(const short8*)(&Bs[r*64 + ck*8]);
            }
            #pragma unroll
            for (int mt = 0; mt < 4; ++mt)
                #pragma unroll
                for (int nt = 0; nt < 4; ++nt)
                    acc[mt][nt] = __builtin_amdgcn_mfma_f32_16x16x32_bf16(af[mt], bf[nt], acc[mt][nt], 0, 0, 0);
        }
        __syncthreads();
    }

    // ---- epilogue: per mt, LDS transpose -> coalesced 16B stores ----
    bool lastbn = (bn == (VV >> 7));   // 392: tile has only VV-50176=81 valid cols
    #pragma unroll
    for (int mt = 0; mt < 4; ++mt) {
        #pragma unroll
        for (int nt = 0; nt < 4; ++nt)
            #pragma unroll
            for (int r = 0; r < 4; ++r)
                ebuf[(wr*16 + quad*4 + r)*132 + wc*64 + nt*16 + l16] = acc[mt][nt][r];
        __syncthreads();
        #pragma unroll
        for (int p = 0; p < 4; ++p) {
            int idx = p*256 + tid;       // 0..1023
            int row = idx >> 5;          // 0..31
            int col = (idx & 31) * 4;    // 0..124
            float4 v = *(const float4*)(&ebuf[row*132 + col]);
            float o0 = fast_tanh15(v.x);
            float o1 = fast_tanh15(v.y);
            float o2 = fast_tanh15(v.z);
            float o3 = fast_tanh15(v.w);
            int grow = bm*128 + (row >> 4)*64 + mt*16 + (row & 15);
            int gcol = bn*128 + col;
            if (!lastbn) {
                f4u s; s.x = o0; s.y = o1; s.z = o2; s.w = o3;
                *(f4u*)(&out[(size_t)grow*VV + gcol]) = s;
            } else {
                if (gcol + 0 < VV) out[(size_t)grow*VV + gcol + 0] = o0;
                if (gcol + 1 < VV) out[(size_t)grow*VV + gcol + 1] = o1;
                if (gcol + 2 < VV) out[(size_t)grow*VV + gcol + 2] = o2;
                if (gcol + 3 < VV) out[(size_t)grow*VV + gcol + 3] = o3;
            }
        }
        __syncthreads();
    }
}

extern "C" void kernel_launch(void* const* d_in, const int* in_sizes, int n_in,
                              void* d_out, int out_size, void* d_ws, size_t ws_size,
                              hipStream_t stream) {
    (void)in_sizes; (void)n_in; (void)out_size; (void)ws_size;
    const int*   idx       = (const int*)d_in[0];
    const int*   nsteps    = (const int*)d_in[1];
    const float* wte       = (const float*)d_in[2];
    const float* adapters  = (const float*)d_in[3];
    const float* qkv_w     = (const float*)d_in[4];
    const float* attn_proj = (const float*)d_in[5];
    const float* mlp_fc    = (const float*)d_in[6];
    const float* mlp_proj  = (const float*)d_in[7];
    const float* dep       = (const float*)d_in[8];
    const float* router_w  = (const float*)d_in[9];
    const float* router_b  = (const float*)d_in[10];
    const float* lm_head   = (const float*)d_in[11];
    float* out = (float*)d_out;
    float* ws  = (float*)d_ws;

    float* depths = ws + OFF_DEPTHS;
    float* aps    = ws + OFF_APS;
    float* mps    = ws + OFF_MPS;
    float* ctab   = ws + OFF_COS;
    float* stab   = ws + OFF_SIN;
    float* x      = ws + OFF_X;
    float* pcont  = ws + OFF_PCONT;
    float* smlp   = ws + OFF_SMLP;
    float* xi     = ws + OFF_XI;
    float* att    = ws + OFF_ATT;
    __hip_bfloat16* xbf  = (__hip_bfloat16*)(ws + OFF_XBF);
    __hip_bfloat16* qb   = (__hip_bfloat16*)(ws + OFF_QB);
    __hip_bfloat16* kb   = (__hip_bfloat16*)(ws + OFF_KB);
    __hip_bfloat16* vtb  = (__hip_bfloat16*)(ws + OFF_VTB);
    __hip_bfloat16* abf  = (__hip_bfloat16*)(ws + OFF_ABF);
    __hip_bfloat16* qwbf = (__hip_bfloat16*)(ws + OFF_QWBF);
    __hip_bfloat16* fwbf = (__hip_bfloat16*)(ws + OFF_FWBF);
    __hip_bfloat16* wbf  = (__hip_bfloat16*)(ws + OFF_WBF);
    __hip_bfloat16* ybf  = (__hip_bfloat16*)(ws + OFF_YBF);

    k_prep<<<1, 64, 0, stream>>>(dep, depths);
    k_sums<<<(NN*GD + 255)/256, 256, 0, stream>>>(attn_proj, mlp_proj, aps, mps);
    k_rope_table<<<(TT*D2 + 255)/256, 256, 0, stream>>>(ctab, stab);
    k_cvt<<<(NN*GD*EE/4 + 255)/256, 256, 0, stream>>>(adapters, abf, NN*GD*EE/4);
    k_cvt<<<(NN*192*GD/4 + 255)/256, 256, 0, stream>>>(qkv_w, qwbf, NN*192*GD/4);
    k_cvt<<<(NN*256*GD/4 + 255)/256, 256, 0, stream>>>(mlp_fc, fwbf, NN*256*GD/4);
    k_embed<<<BT, 256, 0, stream>>>(idx, wte, x, xbf, pcont);

    for (int t = 0; t < 8; ++t) {
        k_xi_qkv<<<dim3(BT/64, NN), 256, 0, stream>>>(xbf, abf, qwbf, x, xi, qb, kb, vtb,
                                                      ctab, stab, depths, nsteps, t);
        k_attn<<<dim3(4, BB, NN), 256, 0, stream>>>(qb, kb, vtb, att, depths, nsteps, t);
        k_fc2<<<dim3(BT/64, NN), 256, 0, stream>>>(xi, att, aps, fwbf, smlp, depths, nsteps, t);
        k_update<<<BT, 256, 0, stream>>>(x, xbf, pcont, att, smlp, aps, mps,
                                         router_w, router_b, depths, nsteps, t,
                                         (t == 7) ? 1 : 0, ybf);
    }

    k_cvt<<<((VV*EE)/4 + 255)/256, 256, 0, stream>>>(lm_head, wbf, (VV*EE)/4);
    k_lmhead<<<1600, 256, 0, stream>>>(ybf, wbf, out);
}

// Round 8
// 695.633 us; speedup vs baseline: 1.0270x; 1.0270x over previous
//
#include <hip/hip_runtime.h>
#include <hip/hip_bf16.h>
#include <math.h>

// Problem constants (from reference)
#define BB 2
#define TT 256
#define BT 512      // B*T
#define EE 512
#define GG 8
#define GD 64
#define LL 8
#define NN 64
#define VV 50257
#define D2 32
#define EPS 1.1920928955078125e-07f
#define S72 72      // LDS row stride in bf16 (144 B -> 2-way bank alias = free)

typedef __attribute__((ext_vector_type(4))) float floatx4;
typedef __attribute__((ext_vector_type(8))) short short8;

// unaligned-capable 16B store (out rows have odd dword stride VV=50257)
struct __attribute__((packed, aligned(4))) f4u { float x, y, z, w; };

// ---------------- workspace layout (float offsets) ----------------
#define OFF_DEPTHS   0
#define OFF_APS      64
#define OFF_MPS      (OFF_APS + NN*GD)            // 4160
#define OFF_COS      (OFF_MPS + NN*GD)            // 8256
#define OFF_SIN      (OFF_COS + TT*D2)            // 16448
#define OFF_X        (OFF_SIN + TT*D2)            // 24640
#define OFF_PCONT    (OFF_X + BT*EE)              // 286784
#define OFF_SMLP     (OFF_PCONT + BT)             // 287296
#define OFF_YBF      (OFF_SMLP + BT*NN)           // 320064 (bf16 BT*EE)
// step-loop region (dead after loop; wbf overlays it)
#define OFF_STEP     (OFF_YBF + (BT*EE)/2)        // 451136
#define OFF_XI       OFF_STEP                     // fp32 BT*NN*GD
#define OFF_ATT      (OFF_XI + BT*NN*GD)          // fp32
#define OFF_XBF      (OFF_ATT + BT*NN*GD)         // bf16 BT*EE
#define OFF_QB       (OFF_XBF + (BT*EE)/2)        // bf16 BT*NN*GD
#define OFF_KB       (OFF_QB + (BT*NN*GD)/2)
#define OFF_VTB      (OFF_KB + (BT*NN*GD)/2)      // bf16, transposed [b][n][g][t]
#define OFF_ABF      (OFF_VTB + (BT*NN*GD)/2)     // bf16 NN*GD*EE
#define OFF_QWBF     (OFF_ABF + (NN*GD*EE)/2)     // bf16 NN*192*GD
#define OFF_FWBF     (OFF_QWBF + (NN*192*GD)/2)   // bf16 NN*256*GD
// after step loop: wbf overlays OFF_STEP..
#define OFF_WBF      OFF_STEP                     // bf16 VV*EE

__device__ __forceinline__ float step_weight(const float* depths, const int* ns, int t, int n) {
    float td = (float)t * (8.0f / (float)ns[0]);
    float wa = expf(-fabsf(depths[n] - td));
    return (wa > 0.15f) ? wa : 0.0f;
}

__device__ __forceinline__ float fast_tanh15(float v) {
    // 15*tanh(v/15) = 15*(1 - 2/(e^{2v/15}+1)); fast exp+div, err << bf16 noise
    float u = v * (1.f/15.f);
    float e = __expf(2.f * u);
    return 15.f * (1.f - __fdividef(2.f, e + 1.f));
}

__global__ void k_prep(const float* __restrict__ dep, float* __restrict__ depths) {
    __shared__ float cur[NN], nxt[NN];
    int i = threadIdx.x;
    if (i < NN) cur[i] = 0.f;
    __syncthreads();
    for (int it = 0; it < LL; ++it) {
        if (i < NN) {
            float acc = 0.f;
            for (int m = 0; m < NN; ++m) acc += fmaxf(dep[i*NN + m], 0.f) * (cur[m] + 1.f);
            nxt[i] = acc;
        }
        __syncthreads();
        if (i < NN) cur[i] = nxt[i];
        __syncthreads();
    }
    if (i < NN) depths[i] = cur[i];
}

__global__ void k_sums(const float* __restrict__ attn_proj, const float* __restrict__ mlp_proj,
                       float* __restrict__ aps, float* __restrict__ mps) {
    int i = blockIdx.x * blockDim.x + threadIdx.x;
    if (i >= NN*GD) return;
    float a = 0.f;
    const float* ap = attn_proj + (size_t)i * GD;
    for (int k = 0; k < GD; ++k) a += ap[k];
    aps[i] = a;
    float m = 0.f;
    const float* mp = mlp_proj + (size_t)i * 4 * GD;
    for (int k = 0; k < 4*GD; ++k) m += mp[k];
    mps[i] = m;
}

__global__ void k_rope_table(float* __restrict__ ctab, float* __restrict__ stab) {
    int i = blockIdx.x * blockDim.x + threadIdx.x;
    if (i >= TT*D2) return;
    int pos = i / D2, f = i % D2;
    double inv = pow(10000.0, -((double)(2*f)) / (double)GD);
    double ang = (double)pos * inv;
    ctab[i] = (float)cos(ang);
    stab[i] = (float)sin(ang);
}

// generic f32 -> bf16 (4 elems/thread), packed 8B store
__global__ void k_cvt(const float* __restrict__ src, __hip_bfloat16* __restrict__ dst, int n4) {
    int i = blockIdx.x * blockDim.x + threadIdx.x;
    if (i >= n4) return;
    float4 f = ((const float4*)src)[i];
    __hip_bfloat16 h0 = __float2bfloat16(f.x);
    __hip_bfloat16 h1 = __float2bfloat16(f.y);
    __hip_bfloat16 h2 = __float2bfloat16(f.z);
    __hip_bfloat16 h3 = __float2bfloat16(f.w);
    ushort4 o;
    o.x = *(const unsigned short*)&h0;
    o.y = *(const unsigned short*)&h1;
    o.z = *(const unsigned short*)&h2;
    o.w = *(const unsigned short*)&h3;
    *(ushort4*)(dst + (size_t)i*4) = o;
}

__global__ void k_embed(const int* __restrict__ idx, const float* __restrict__ wte,
                        float* __restrict__ x, __hip_bfloat16* __restrict__ xbf,
                        float* __restrict__ pcont) {
    int bt = blockIdx.x;
    int tid = threadIdx.x;
    const float* src = wte + (size_t)idx[bt] * EE;
    float v0 = src[tid], v1 = src[tid + 256];
    __shared__ float red[4];
    float ss = v0*v0 + v1*v1;
    for (int o = 32; o > 0; o >>= 1) ss += __shfl_xor(ss, o);
    if ((tid & 63) == 0) red[tid >> 6] = ss;
    __syncthreads();
    float sc = rsqrtf((red[0]+red[1]+red[2]+red[3]) / (float)EE + EPS);
    float a = v0 * sc, b = v1 * sc;
    x[bt*EE + tid]       = a;
    x[bt*EE + tid + 256] = b;
    xbf[bt*EE + tid]       = __float2bfloat16(a);
    xbf[bt*EE + tid + 256] = __float2bfloat16(b);
    if (tid == 0) pcont[bt] = 1.f;
}

// ---- Fused xi + qkv + rope + rms, bf16 MFMA.  grid (BT/64, NN), 256 thr. ----
// Phase-1: linear [2][64][64] LDS tiles staged by global_load_lds width-16,
// chunk-XOR swizzle on source+read, 2-phase prefetch dbuf (WIN: latency-bound
// at ~192 blocks, prefetch is the only latency hider). 42.2 KB LDS.
__global__ __launch_bounds__(256) void k_xi_qkv(const __hip_bfloat16* __restrict__ xbf,
        const __hip_bfloat16* __restrict__ abf, const __hip_bfloat16* __restrict__ qwbf,
        const float* __restrict__ x, float* __restrict__ xi,
        __hip_bfloat16* __restrict__ qb, __hip_bfloat16* __restrict__ kb,
        __hip_bfloat16* __restrict__ vtb,
        const float* __restrict__ ctab, const float* __restrict__ stab,
        const float* __restrict__ depths, const int* __restrict__ ns, int t) {
    int n = blockIdx.y;
    if (step_weight(depths, ns, t, n) == 0.f) return;
    int bt0 = blockIdx.x * 64;
    // region0 [0,16640): obuf(fp32 64*65) ∪ sA[2][4096]
    // region1 [16640,33024): sB[2][4096] ∪ Bs72[64*S72]
    // region2 [33024,42240): xis[64*S72]
    __shared__ __align__(16) char smem[16640 + 16384 + 9216];
    __hip_bfloat16* sA   = (__hip_bfloat16*)smem;
    float*          obuf = (float*)smem;
    __hip_bfloat16* sB   = (__hip_bfloat16*)(smem + 16640);
    __hip_bfloat16* Bs72 = (__hip_bfloat16*)(smem + 16640);
    __hip_bfloat16* xis  = (__hip_bfloat16*)(smem + 33024);
    int tid = threadIdx.x;
    int wave = tid >> 6, lane = tid & 63;
    int wr = wave >> 1, wc = wave & 1;
    int quad = lane >> 4, l16 = lane & 15;

    // ---- phase 1: xi = xbf @ abf[n]^T  (64 tok x 64 g, K=512) ----
    size_t goffA[2], goffB[2];
    int sOff[2];
    #pragma unroll
    for (int j = 0; j < 2; ++j) {
        int s = (j*4 + wave)*64 + lane;   // chunk id 0..511
        int r = s >> 3;                   // tile row 0..63
        int cs = (s & 7) ^ (r & 7);       // swizzled source chunk
        goffA[j] = (size_t)(bt0 + r)*EE + cs*8;
        goffB[j] = ((size_t)n*GD + r)*EE + cs*8;
        sOff[j] = (j*4 + wave)*512;       // bf16 elems; wave-uniform
    }

    floatx4 acc[2][2];
    #pragma unroll
    for (int mt = 0; mt < 2; ++mt)
        #pragma unroll
        for (int nt = 0; nt < 2; ++nt) acc[mt][nt] = (floatx4){0.f,0.f,0.f,0.f};

    // prologue: stage kt=0 into buffer 0
    #pragma unroll
    for (int j = 0; j < 2; ++j) {
        __builtin_amdgcn_global_load_lds(
            (const __attribute__((address_space(1))) void*)(xbf + goffA[j]),
            (__attribute__((address_space(3))) void*)(&sA[sOff[j]]), 16, 0, 0);
        __builtin_amdgcn_global_load_lds(
            (const __attribute__((address_space(1))) void*)(abf + goffB[j]),
            (__attribute__((address_space(3))) void*)(&sB[sOff[j]]), 16, 0, 0);
    }
    __syncthreads();

    int cur = 0;
    #pragma unroll
    for (int kt = 0; kt < 8; ++kt) {
        if (kt < 7) {
            int k0 = (kt + 1) * 64;
            #pragma unroll
            for (int j = 0; j < 2; ++j) {
                __builtin_amdgcn_global_load_lds(
                    (const __attribute__((address_space(1))) void*)(xbf + goffA[j] + k0),
                    (__attribute__((address_space(3))) void*)(&sA[(cur^1)*4096 + sOff[j]]), 16, 0, 0);
                __builtin_amdgcn_global_load_lds(
                    (const __attribute__((address_space(1))) void*)(abf + goffB[j] + k0),
                    (__attribute__((address_space(3))) void*)(&sB[(cur^1)*4096 + sOff[j]]), 16, 0, 0);
            }
        }
        #pragma unroll
        for (int ks = 0; ks < 2; ++ks) {
            short8 af[2], bf[2];
            #pragma unroll
            for (int mt = 0; mt < 2; ++mt) {
                int row = wr*32 + mt*16 + l16;
                int ck = ((ks << 2) | quad) ^ (row & 7);
                af[mt] = *(const short8*)(&sA[cur*4096 + row*64 + ck*8]);
            }
            #pragma unroll
            for (int nt = 0; nt < 2; ++nt) {
                int row = wc*32 + nt*16 + l16;
                int ck = ((ks << 2) | quad) ^ (row & 7);
                bf[nt] = *(const short8*)(&sB[cur*4096 + row*64 + ck*8]);
            }
            #pragma unroll
            for (int mt = 0; mt < 2; ++mt)
                #pragma unroll
                for (int nt = 0; nt < 2; ++nt)
                    acc[mt][nt] = __builtin_amdgcn_mfma_f32_16x16x32_bf16(af[mt], bf[nt], acc[mt][nt], 0, 0, 0);
        }
        __syncthreads();
        cur ^= 1;
    }

    int gofs = (n & (GG-1)) * GD;
    #pragma unroll
    for (int mt = 0; mt < 2; ++mt) {
        #pragma unroll
        for (int nt = 0; nt < 2; ++nt) {
            int col = wc*32 + nt*16 + l16;
            #pragma unroll
            for (int r = 0; r < 4; ++r) {
                int token = wr*32 + mt*16 + quad*4 + r;
                int bt = bt0 + token;
                float val = acc[mt][nt][r] + x[(size_t)bt*EE + gofs + col];
                xi[((size_t)bt*NN + n)*GD + col] = val;
                xis[token*S72 + col] = __float2bfloat16(val);
            }
        }
    }
    __syncthreads();

    // ---- phase 2: qkv = xis @ qkv_w[n]^T (per c: 64 tok x 64 out, K=64) ----
    const __hip_bfloat16* wbase = qwbf + (size_t)n * 192 * GD;
    int b = bt0 >> 8;           // batch index
    int t0 = bt0 & (TT - 1);    // position of first token in tile
    for (int c = 0; c < 3; ++c) {
        for (int i = tid; i < 512; i += 256) {
            int r = i >> 3, c8 = (i & 7) * 8;
            *(uint4*)(&Bs72[r*S72 + c8]) = *(const uint4*)(&wbase[(size_t)(c*64 + r)*GD + c8]);
        }
        __syncthreads();
        floatx4 oacc[2][2];
        #pragma unroll
        for (int mt = 0; mt < 2; ++mt)
            #pragma unroll
            for (int nt = 0; nt < 2; ++nt) oacc[mt][nt] = (floatx4){0.f,0.f,0.f,0.f};
        #pragma unroll
        for (int ks = 0; ks < 2; ++ks) {
            short8 af[2], bf[2];
            #pragma unroll
            for (int mt = 0; mt < 2; ++mt)
                af[mt] = *(const short8*)(&xis[(wr*32 + mt*16 + l16)*S72 + ks*32 + quad*8]);
            #pragma unroll
            for (int nt = 0; nt < 2; ++nt)
                bf[nt] = *(const short8*)(&Bs72[(wc*32 + nt*16 + l16)*S72 + ks*32 + quad*8]);
            #pragma unroll
            for (int mt = 0; mt < 2; ++mt)
                #pragma unroll
                for (int nt = 0; nt < 2; ++nt)
                    oacc[mt][nt] = __builtin_amdgcn_mfma_f32_16x16x32_bf16(af[mt], bf[nt], oacc[mt][nt], 0, 0, 0);
        }
        #pragma unroll
        for (int mt = 0; mt < 2; ++mt)
            #pragma unroll
            for (int nt = 0; nt < 2; ++nt)
                #pragma unroll
                for (int r = 0; r < 4; ++r)
                    obuf[(wr*32 + mt*16 + quad*4 + r)*65 + wc*32 + nt*16 + l16] = oacc[mt][nt][r];
        __syncthreads();
        if (c < 2) {
            // rope + rms per token-row, write bf16
            __hip_bfloat16* dst = (c == 0) ? qb : kb;
            for (int tr = 0; tr < 16; ++tr) {
                int row = wave*16 + tr, bt = bt0 + row;
                float val = obuf[row*65 + lane];
                int pos = bt & (TT - 1);
                float pair = __shfl_xor(val, 32);
                int fi = lane & 31;
                float cc = ctab[pos*D2 + fi], sn = stab[pos*D2 + fi];
                float nv = (lane < 32) ? (val*cc + pair*sn) : (val*cc - pair*sn);
                float ss = nv*nv;
                for (int o = 32; o > 0; o >>= 1) ss += __shfl_xor(ss, o);
                float outv = nv * rsqrtf(ss / (float)GD + EPS);
                dst[((size_t)bt*NN + n)*GD + lane] = __float2bfloat16(outv);
            }
        } else {
            // v: read obuf transposed (conflict-free), write coalesced to vtb[b][n][g][t]
            for (int tr = 0; tr < 16; ++tr) {
                int g = wave*16 + tr;
                float vv = obuf[lane*65 + g];
                vtb[(((size_t)(b*NN + n))*GD + g)*TT + t0 + lane] = __float2bfloat16(vv);
            }
        }
        __syncthreads();
    }
}

// ---- Flash attention, bf16 MFMA.  grid (4, B, NN), 256 thr (4 waves, 16 rows each). ----
// K/V tiles: linear [2][64x64] dbuf staged by global_load_lds + chunk-XOR swizzle
// (xi_qkv-verified pattern); prefetch ct+1 issued before QK^T overlaps QK^T+softmax.
__global__ __launch_bounds__(256) void k_attn(const __hip_bfloat16* __restrict__ qb,
        const __hip_bfloat16* __restrict__ kb, const __hip_bfloat16* __restrict__ vtb,
        float* __restrict__ att,
        const float* __restrict__ depths, const int* __restrict__ ns, int t) {
    int it = blockIdx.x, b = blockIdx.y, n = blockIdx.z;
    if (step_weight(depths, ns, t, n) == 0.f) return;
    __shared__ __align__(16) __hip_bfloat16 qs[64*S72];
    __shared__ __align__(16) __hip_bfloat16 ksm[2][4096];
    __shared__ __align__(16) __hip_bfloat16 vs[2][4096];
    __shared__ __align__(16) __hip_bfloat16 ps[64*S72];
    int tid = threadIdx.x;
    int wave = tid >> 6, lane = tid & 63;
    int quad = lane >> 4, l16 = lane & 15;

    // staging descriptors (512 16B-chunks per 64x64 tile; 2 issues/thread per tile)
    size_t koff[2], voff[2];
    int sOff[2];
    #pragma unroll
    for (int j = 0; j < 2; ++j) {
        int s = (j*4 + wave)*64 + lane;   // chunk id 0..511
        int r = s >> 3;                   // tile row 0..63
        int cs = (s & 7) ^ (r & 7);       // swizzled source chunk
        koff[j] = (((size_t)(b*TT + r))*NN + n)*GD + cs*8;        // + ct*64*NN*GD
        voff[j] = (((size_t)(b*NN + n))*GD + r)*TT + cs*8;        // + ct*64
        sOff[j] = (j*4 + wave)*512;
    }

    // stage ct=0 K/V into buffer 0 (overlaps with q load below)
    #pragma unroll
    for (int j = 0; j < 2; ++j) {
        __builtin_amdgcn_global_load_lds(
            (const __attribute__((address_space(1))) void*)(kb + koff[j]),
            (__attribute__((address_space(3))) void*)(&ksm[0][sOff[j]]), 16, 0, 0);
        __builtin_amdgcn_global_load_lds(
            (const __attribute__((address_space(1))) void*)(vtb + voff[j]),
            (__attribute__((address_space(3))) void*)(&vs[0][sOff[j]]), 16, 0, 0);
    }
    for (int i = tid; i < 512; i += 256) {
        int r = i >> 3, c8 = (i & 7) * 8;
        *(uint4*)(&qs[r*S72 + c8]) = *(const uint4*)(&qb[(((size_t)(b*TT + it*64 + r))*NN + n)*GD + c8]);
    }
    floatx4 oacc[4];
    float m_i[4], l_i[4];
    #pragma unroll
    for (int nt = 0; nt < 4; ++nt) oacc[nt] = (floatx4){0.f,0.f,0.f,0.f};
    #pragma unroll
    for (int r = 0; r < 4; ++r) { m_i[r] = -INFINITY; l_i[r] = 0.f; }
    __syncthreads();

    int cur = 0;
    for (int ct = 0; ct <= it; ++ct) {
        // prefetch ct+1 (latency hides under QK^T + softmax)
        if (ct < it) {
            size_t kadd = (size_t)(ct + 1) * 64 * NN * GD;
            size_t vadd = (size_t)(ct + 1) * 64;
            #pragma unroll
            for (int j = 0; j < 2; ++j) {
                __builtin_amdgcn_global_load_lds(
                    (const __attribute__((address_space(1))) void*)(kb + koff[j] + kadd),
                    (__attribute__((address_space(3))) void*)(&ksm[cur^1][sOff[j]]), 16, 0, 0);
                __builtin_amdgcn_global_load_lds(
                    (const __attribute__((address_space(1))) void*)(vtb + voff[j] + vadd),
                    (__attribute__((address_space(3))) void*)(&vs[cur^1][sOff[j]]), 16, 0, 0);
            }
        }
        // S = Q K^T : rows = wave*16.., cols = full 64
        floatx4 s[4];
        #pragma unroll
        for (int nt = 0; nt < 4; ++nt) s[nt] = (floatx4){0.f,0.f,0.f,0.f};
        #pragma unroll
        for (int ks = 0; ks < 2; ++ks) {
            short8 af = *(const short8*)(&qs[(wave*16 + l16)*S72 + ks*32 + quad*8]);
            #pragma unroll
            for (int nt = 0; nt < 4; ++nt) {
                int row = nt*16 + l16;
                int ck = ((ks << 2) | quad) ^ (row & 7);
                short8 bf = *(const short8*)(&ksm[cur][row*64 + ck*8]);
                s[nt] = __builtin_amdgcn_mfma_f32_16x16x32_bf16(af, bf, s[nt], 0, 0, 0);
            }
        }
        // online softmax per row (row = wave*16 + quad*4 + r)
        #pragma unroll
        for (int r = 0; r < 4; ++r) {
            int rowg = it*64 + wave*16 + quad*4 + r;
            float mx = -INFINITY;
            #pragma unroll
            for (int nt = 0; nt < 4; ++nt) {
                int colg = ct*64 + nt*16 + l16;
                float sv = (colg <= rowg) ? s[nt][r] * 0.125f : -INFINITY;
                s[nt][r] = sv;
                mx = fmaxf(mx, sv);
            }
            for (int o = 8; o > 0; o >>= 1) mx = fmaxf(mx, __shfl_xor(mx, o));
            float mnew = fmaxf(m_i[r], mx);
            float alpha = expf(m_i[r] - mnew);
            float rs = 0.f;
            #pragma unroll
            for (int nt = 0; nt < 4; ++nt) {
                float p = expf(s[nt][r] - mnew);
                s[nt][r] = p;
                rs += p;
            }
            for (int o = 8; o > 0; o >>= 1) rs += __shfl_xor(rs, o);
            l_i[r] = l_i[r]*alpha + rs;
            m_i[r] = mnew;
            #pragma unroll
            for (int nt = 0; nt < 4; ++nt) oacc[nt][r] *= alpha;
        }
        // P -> LDS (A-layout rows = q-token)
        #pragma unroll
        for (int nt = 0; nt < 4; ++nt)
            #pragma unroll
            for (int r = 0; r < 4; ++r)
                ps[(wave*16 + quad*4 + r)*S72 + nt*16 + l16] = __float2bfloat16(s[nt][r]);
        __syncthreads();
        // O += P V : B-operand rows = g (vtb transposed), k = ct-token
        #pragma unroll
        for (int ks = 0; ks < 2; ++ks) {
            short8 af = *(const short8*)(&ps[(wave*16 + l16)*S72 + ks*32 + quad*8]);
            #pragma unroll
            for (int nt = 0; nt < 4; ++nt) {
                int row = nt*16 + l16;
                int ck = ((ks << 2) | quad) ^ (row & 7);
                short8 bf = *(const short8*)(&vs[cur][row*64 + ck*8]);
                oacc[nt] = __builtin_amdgcn_mfma_f32_16x16x32_bf16(af, bf, oacc[nt], 0, 0, 0);
            }
        }
        __syncthreads();   // drains prefetch vmcnt + protects ps & buffer swap
        cur ^= 1;
    }
    #pragma unroll
    for (int r = 0; r < 4; ++r) {
        float inv = 1.f / l_i[r];
        int token = it*64 + wave*16 + quad*4 + r;
        #pragma unroll
        for (int nt = 0; nt < 4; ++nt)
            att[((size_t)(b*TT + token)*NN + n)*GD + nt*16 + l16] = oacc[nt][r] * inv;
    }
}

// ---- fc: smlp = sum_o relu(mlp_fc[n] @ rms(xi+att*aps))^2, bf16 MFMA.  grid (BT/64, NN). ----
// Weight tiles: linear [2][64x64] dbuf via global_load_lds + chunk-XOR (contiguous
// 8 KB source tiles); c=0 staging overlaps the ys rms loop; prefetch c+1 during MFMA.
__global__ __launch_bounds__(256) void k_fc2(const float* __restrict__ xi, const float* __restrict__ att,
        const float* __restrict__ aps, const __hip_bfloat16* __restrict__ fwbf, float* __restrict__ smlp,
        const float* __restrict__ depths, const int* __restrict__ ns, int t) {
    int n = blockIdx.y;
    if (step_weight(depths, ns, t, n) == 0.f) return;
    int bt0 = blockIdx.x * 64;
    __shared__ __align__(16) __hip_bfloat16 ys[64*S72];
    __shared__ __align__(16) __hip_bfloat16 ws[2][4096];
    __shared__ float sred[64];
    int tid = threadIdx.x;
    int wave = tid >> 6, lane = tid & 63;
    int quad = lane >> 4, l16 = lane & 15;

    // staging descriptors for 64x64 weight tile (contiguous 4096 elems per c)
    const __hip_bfloat16* wtile = fwbf + (size_t)n * 256 * GD;
    size_t woff[2];
    int sOff[2];
    #pragma unroll
    for (int j = 0; j < 2; ++j) {
        int s = (j*4 + wave)*64 + lane;
        int r = s >> 3;
        int cs = (s & 7) ^ (r & 7);
        woff[j] = (size_t)r*GD + cs*8;     // + c*4096
        sOff[j] = (j*4 + wave)*512;
    }
    // stage c=0 (overlaps ys computation below)
    #pragma unroll
    for (int j = 0; j < 2; ++j)
        __builtin_amdgcn_global_load_lds(
            (const __attribute__((address_space(1))) void*)(wtile + woff[j]),
            (__attribute__((address_space(3))) void*)(&ws[0][sOff[j]]), 16, 0, 0);

    for (int tr = 0; tr < 16; ++tr) {
        int row = wave*16 + tr, bt = bt0 + row;
        size_t base = ((size_t)bt*NN + n)*GD + lane;
        float xv = xi[base] + att[base] * aps[n*GD + lane];
        float ss = xv*xv;
        for (int o = 32; o > 0; o >>= 1) ss += __shfl_xor(ss, o);
        ys[row*S72 + lane] = __float2bfloat16(xv * rsqrtf(ss / (float)GD + EPS));
    }
    __syncthreads();

    float rowacc[4] = {0.f, 0.f, 0.f, 0.f};
    int cur = 0;
    #pragma unroll
    for (int c = 0; c < 4; ++c) {
        if (c < 3) {
            #pragma unroll
            for (int j = 0; j < 2; ++j)
                __builtin_amdgcn_global_load_lds(
                    (const __attribute__((address_space(1))) void*)(wtile + (c + 1)*4096 + woff[j]),
                    (__attribute__((address_space(3))) void*)(&ws[cur^1][sOff[j]]), 16, 0, 0);
        }
        floatx4 s[4];
        #pragma unroll
        for (int nt = 0; nt < 4; ++nt) s[nt] = (floatx4){0.f,0.f,0.f,0.f};
        #pragma unroll
        for (int ks = 0; ks < 2; ++ks) {
            short8 af = *(const short8*)(&ys[(wave*16 + l16)*S72 + ks*32 + quad*8]);
            #pragma unroll
            for (int nt = 0; nt < 4; ++nt) {
                int row = nt*16 + l16;
                int ck = ((ks << 2) | quad) ^ (row & 7);
                short8 bf = *(const short8*)(&ws[cur][row*64 + ck*8]);
                s[nt] = __builtin_amdgcn_mfma_f32_16x16x32_bf16(af, bf, s[nt], 0, 0, 0);
            }
        }
        #pragma unroll
        for (int nt = 0; nt < 4; ++nt)
            #pragma unroll
            for (int r = 0; r < 4; ++r) {
                float rr = fmaxf(s[nt][r], 0.f);
                rowacc[r] += rr*rr;
            }
        __syncthreads();   // drains prefetch + protects buffer swap
        cur ^= 1;
    }
    #pragma unroll
    for (int r = 0; r < 4; ++r) {
        for (int o = 8; o > 0; o >>= 1) rowacc[r] += __shfl_xor(rowacc[r], o);
        if (l16 == 0) sred[wave*16 + quad*4 + r] = rowacc[r];
    }
    __syncthreads();
    if (tid < 64) smlp[(size_t)(bt0 + tid)*NN + n] = sred[tid];
}

// last!=0: final step — skip xbf store, fuse rms conversion (write ybf) here.
__global__ __launch_bounds__(256) void k_update(float* __restrict__ x, __hip_bfloat16* __restrict__ xbf,
                                                float* __restrict__ pcont,
                                                const float* __restrict__ att, const float* __restrict__ smlp,
                                                const float* __restrict__ aps, const float* __restrict__ mps,
                                                const float* __restrict__ router_w, const float* __restrict__ router_b,
                                                const float* __restrict__ depths, const int* __restrict__ ns, int t,
                                                int last, __hip_bfloat16* __restrict__ ybf) {
    int bt = blockIdx.x, tid = threadIdx.x;
    __shared__ float we[NN];
    __shared__ float red[4];
    __shared__ float red2[4];
    if (tid < NN) we[tid] = step_weight(depths, ns, t, tid);
    __syncthreads();
    float pc = pcont[bt];
    float dot = 0.f, ssq = 0.f;
    float xv0 = 0.f, xv1 = 0.f;
    #pragma unroll
    for (int h = 0; h < 2; ++h) {
        int e = tid + h*256;
        int gq = e >> 6, gd = e & 63;
        float sum = 0.f;
        #pragma unroll
        for (int l = 0; l < LL; ++l) {
            int n = l*GG + gq;
            float w = we[n];
            if (w != 0.f) {
                sum += (att[((size_t)bt*NN + n)*GD + gd] * aps[n*GD + gd]
                        + smlp[bt*NN + n] * mps[n*GD + gd]) * w;
            }
        }
        float xv = x[bt*EE + e] + sum * pc;
        x[bt*EE + e] = xv;
        if (!last) xbf[bt*EE + e] = __float2bfloat16(xv);
        dot += xv * router_w[e];
        ssq += xv * xv;
        if (h == 0) xv0 = xv; else xv1 = xv;
    }
    for (int o = 32; o > 0; o >>= 1) dot += __shfl_xor(dot, o);
    if (last) for (int o = 32; o > 0; o >>= 1) ssq += __shfl_xor(ssq, o);
    if ((tid & 63) == 0) { red[tid >> 6] = dot; red2[tid >> 6] = ssq; }
    __syncthreads();
    if (last) {
        float sc = rsqrtf((red2[0]+red2[1]+red2[2]+red2[3]) / (float)EE + EPS);
        ybf[bt*EE + tid]       = __float2bfloat16(xv0 * sc);
        ybf[bt*EE + tid + 256] = __float2bfloat16(xv1 * sc);
    }
    if (tid == 0) {
        float z = red[0]+red[1]+red[2]+red[3] + router_b[0];
        float ph = 1.f / (1.f + expf(-z));
        pcont[bt] = pc * (1.f - ph);
    }
}

// out = 15*tanh((rms(x) @ W^T)/15), bf16 MFMA.
// K-loop: single-buffer (32 KB LDS). Chunk-XOR swizzle source+read.
// LDS-transpose epilogue: coalesced 16B stores (88->70 µs verified).
__global__ __launch_bounds__(256) void k_lmhead(const __hip_bfloat16* __restrict__ ybf,
                                                const __hip_bfloat16* __restrict__ wbf,
                                                float* __restrict__ out) {
    int id = blockIdx.x;
    int w = (id & 7) * 200 + (id >> 3);   // bijective chunked XCD swizzle (1600 = 8*200)
    int bm = w & 3;
    int bn = w >> 2;
    if (bn >= (VV + 127)/128) return;

    __shared__ __align__(16) char smem[32768];
    __hip_bfloat16* As  = (__hip_bfloat16*)smem;            // [128*64]
    __hip_bfloat16* Bs  = (__hip_bfloat16*)(smem + 16384);  // [128*64]
    float*          ebuf = (float*)smem;                    // epilogue 32x132 fp32 (16.9 KB)

    int tid = threadIdx.x;
    int wave = tid >> 6, lane = tid & 63;
    int wr = wave >> 1, wc = wave & 1;
    int quad = lane >> 4, l16 = lane & 15;

    size_t offA[4], offB[4];
    int ldsOff[4];
    #pragma unroll
    for (int j = 0; j < 4; ++j) {
        int s = (j*4 + wave)*64 + lane;   // chunk id 0..1023
        int r = s >> 3;                   // tile row 0..127
        int cs = (s & 7) ^ (r & 7);       // swizzled source chunk 0..7
        offA[j] = (size_t)(bm*128 + r)*EE + cs*8;
        int vrow = bn*128 + r; if (vrow >= VV) vrow = VV - 1;
        offB[j] = (size_t)vrow*EE + cs*8;
        ldsOff[j] = (j*4 + wave)*512;     // bf16 elems; wave-uniform
    }

    floatx4 acc[4][4];
    #pragma unroll
    for (int mt = 0; mt < 4; ++mt)
        #pragma unroll
        for (int nt = 0; nt < 4; ++nt)
            acc[mt][nt] = (floatx4){0.f, 0.f, 0.f, 0.f};

    for (int k0 = 0; k0 < EE; k0 += 64) {
        #pragma unroll
        for (int j = 0; j < 4; ++j) {
            __builtin_amdgcn_global_load_lds(
                (const __attribute__((address_space(1))) void*)(ybf + offA[j] + k0),
                (__attribute__((address_space(3))) void*)(&As[ldsOff[j]]), 16, 0, 0);
            __builtin_amdgcn_global_load_lds(
                (const __attribute__((address_space(1))) void*)(wbf + offB[j] + k0),
                (__attribute__((address_space(3))) void*)(&Bs[ldsOff[j]]), 16, 0, 0);
        }
        __syncthreads();
        #pragma unroll
        for (int ks = 0; ks < 2; ++ks) {
            short8 af[4], bf[4];
            #pragma unroll
            for (int mt = 0; mt < 4; ++mt) {
                int r = wr*64 + mt*16 + l16;
                int ck = ((ks << 2) | quad) ^ (r & 7);
                af[mt] = *(const short8*)(&As[r*64 + ck*8]);
            }
            #pragma unroll
            for (int nt = 0; nt < 4; ++nt) {
                int r = wc*64 + nt*16 + l16;
                int ck = ((ks << 2) | quad) ^ (r & 7);
                bf[nt] = *(const short8*)(&Bs[r*64 + ck*8]);
            }
            #pragma unroll
            for (int mt = 0; mt < 4; ++mt)
                #pragma unroll
                for (int nt = 0; nt < 4; ++nt)
                    acc[mt][nt] = __builtin_amdgcn_mfma_f32_16x16x32_bf16(af[mt], bf[nt], acc[mt][nt], 0, 0, 0);
        }
        __syncthreads();
    }

    // ---- epilogue: per mt, LDS transpose -> coalesced 16B stores ----
    bool lastbn = (bn == (VV >> 7));   // 392: tile has only VV-50176=81 valid cols
    #pragma unroll
    for (int mt = 0; mt < 4; ++mt) {
        #pragma unroll
        for (int nt = 0; nt < 4; ++nt)
            #pragma unroll
            for (int r = 0; r < 4; ++r)
                ebuf[(wr*16 + quad*4 + r)*132 + wc*64 + nt*16 + l16] = acc[mt][nt][r];
        __syncthreads();
        #pragma unroll
        for (int p = 0; p < 4; ++p) {
            int idx = p*256 + tid;       // 0..1023
            int row = idx >> 5;          // 0..31
            int col = (idx & 31) * 4;    // 0..124
            float4 v = *(const float4*)(&ebuf[row*132 + col]);
            float o0 = fast_tanh15(v.x);
            float o1 = fast_tanh15(v.y);
            float o2 = fast_tanh15(v.z);
            float o3 = fast_tanh15(v.w);
            int grow = bm*128 + (row >> 4)*64 + mt*16 + (row & 15);
            int gcol = bn*128 + col;
            if (!lastbn) {
                f4u s; s.x = o0; s.y = o1; s.z = o2; s.w = o3;
                *(f4u*)(&out[(size_t)grow*VV + gcol]) = s;
            } else {
                if (gcol + 0 < VV) out[(size_t)grow*VV + gcol + 0] = o0;
                if (gcol + 1 < VV) out[(size_t)grow*VV + gcol + 1] = o1;
                if (gcol + 2 < VV) out[(size_t)grow*VV + gcol + 2] = o2;
                if (gcol + 3 < VV) out[(size_t)grow*VV + gcol + 3] = o3;
            }
        }
        __syncthreads();
    }
}

extern "C" void kernel_launch(void* const* d_in, const int* in_sizes, int n_in,
                              void* d_out, int out_size, void* d_ws, size_t ws_size,
                              hipStream_t stream) {
    (void)in_sizes; (void)n_in; (void)out_size; (void)ws_size;
    const int*   idx       = (const int*)d_in[0];
    const int*   nsteps    = (const int*)d_in[1];
    const float* wte       = (const float*)d_in[2];
    const float* adapters  = (const float*)d_in[3];
    const float* qkv_w     = (const float*)d_in[4];
    const float* attn_proj = (const float*)d_in[5];
    const float* mlp_fc    = (const float*)d_in[6];
    const float* mlp_proj  = (const float*)d_in[7];
    const float* dep       = (const float*)d_in[8];
    const float* router_w  = (const float*)d_in[9];
    const float* router_b  = (const float*)d_in[10];
    const float* lm_head   = (const float*)d_in[11];
    float* out = (float*)d_out;
    float* ws  = (float*)d_ws;

    float* depths = ws + OFF_DEPTHS;
    float* aps    = ws + OFF_APS;
    float* mps    = ws + OFF_MPS;
    float* ctab   = ws + OFF_COS;
    float* stab   = ws + OFF_SIN;
    float* x      = ws + OFF_X;
    float* pcont  = ws + OFF_PCONT;
    float* smlp   = ws + OFF_SMLP;
    float* xi     = ws + OFF_XI;
    float* att    = ws + OFF_ATT;
    __hip_bfloat16* xbf  = (__hip_bfloat16*)(ws + OFF_XBF);
    __hip_bfloat16* qb   = (__hip_bfloat16*)(ws + OFF_QB);
    __hip_bfloat16* kb   = (__hip_bfloat16*)(ws + OFF_KB);
    __hip_bfloat16* vtb  = (__hip_bfloat16*)(ws + OFF_VTB);
    __hip_bfloat16* abf  = (__hip_bfloat16*)(ws + OFF_ABF);
    __hip_bfloat16* qwbf = (__hip_bfloat16*)(ws + OFF_QWBF);
    __hip_bfloat16* fwbf = (__hip_bfloat16*)(ws + OFF_FWBF);
    __hip_bfloat16* wbf  = (__hip_bfloat16*)(ws + OFF_WBF);
    __hip_bfloat16* ybf  = (__hip_bfloat16*)(ws + OFF_YBF);

    k_prep<<<1, 64, 0, stream>>>(dep, depths);
    k_sums<<<(NN*GD + 255)/256, 256, 0, stream>>>(attn_proj, mlp_proj, aps, mps);
    k_rope_table<<<(TT*D2 + 255)/256, 256, 0, stream>>>(ctab, stab);
    k_cvt<<<(NN*GD*EE/4 + 255)/256, 256, 0, stream>>>(adapters, abf, NN*GD*EE/4);
    k_cvt<<<(NN*192*GD/4 + 255)/256, 256, 0, stream>>>(qkv_w, qwbf, NN*192*GD/4);
    k_cvt<<<(NN*256*GD/4 + 255)/256, 256, 0, stream>>>(mlp_fc, fwbf, NN*256*GD/4);
    k_embed<<<BT, 256, 0, stream>>>(idx, wte, x, xbf, pcont);

    for (int t = 0; t < 8; ++t) {
        k_xi_qkv<<<dim3(BT/64, NN), 256, 0, stream>>>(xbf, abf, qwbf, x, xi, qb, kb, vtb,
                                                      ctab, stab, depths, nsteps, t);
        k_attn<<<dim3(4, BB, NN), 256, 0, stream>>>(qb, kb, vtb, att, depths, nsteps, t);
        k_fc2<<<dim3(BT/64, NN), 256, 0, stream>>>(xi, att, aps, fwbf, smlp, depths, nsteps, t);
        k_update<<<BT, 256, 0, stream>>>(x, xbf, pcont, att, smlp, aps, mps,
                                         router_w, router_b, depths, nsteps, t,
                                         (t == 7) ? 1 : 0, ybf);
    }

    k_cvt<<<((VV*EE)/4 + 255)/256, 256, 0, stream>>>(lm_head, wbf, (VV*EE)/4);
    k_lmhead<<<1600, 256, 0, stream>>>(ybf, wbf, out);
}